// Round 1
// baseline (108.377 us; speedup 1.0000x reference)
//
#include <hip/hip_runtime.h>

// Shapes from reference: n=32, p2=49, topk=4, w2=64, c_kv=256
// out[b,p,t,w,c] = r_weight[b,p,t] * kv[b, r_idx[b,p,t], w, c]
constexpr int N    = 32;
constexpr int P2   = 49;
constexpr int TOPK = 4;
constexpr int W2   = 64;
constexpr int CKV  = 256;
constexpr int ROW  = W2 * CKV;      // 16384 floats per gathered slab (64 KB)
constexpr int ROW4 = ROW / 4;       // 4096 float4 per slab

__global__ __launch_bounds__(256)
void kv_gather_scale(const int* __restrict__ r_idx,
                     const float* __restrict__ r_weight,
                     const float* __restrict__ kv,
                     float* __restrict__ out) {
    const int g = blockIdx.x;                 // flat (b, p, t) in [0, N*P2*TOPK)
    const int b = g / (P2 * TOPK);

    const int   src = r_idx[g];               // source p-row in [0, P2)
    const float w   = r_weight[g];

    const float4* __restrict__ s =
        (const float4*)(kv + (size_t)(b * P2 + src) * ROW);
    float4* __restrict__ d = (float4*)(out + (size_t)g * ROW);

    #pragma unroll 4
    for (int i = threadIdx.x; i < ROW4; i += 256) {
        float4 v = s[i];
        v.x *= w; v.y *= w; v.z *= w; v.w *= w;
        d[i] = v;
    }
}

extern "C" void kernel_launch(void* const* d_in, const int* in_sizes, int n_in,
                              void* d_out, int out_size, void* d_ws, size_t ws_size,
                              hipStream_t stream) {
    const int*   r_idx    = (const int*)d_in[0];
    const float* r_weight = (const float*)d_in[1];
    const float* kv       = (const float*)d_in[2];
    float*       out      = (float*)d_out;

    const int nblocks = N * P2 * TOPK;        // 6272
    kv_gather_scale<<<nblocks, 256, 0, stream>>>(r_idx, r_weight, kv, out);
}